// Round 1
// baseline (1874.258 us; speedup 1.0000x reference)
//
#include <hip/hip_runtime.h>
#include <math.h>

#define N_NODES 50000
#define N_EDGES 1600000
#define IN_CH 32
#define HID 64

// Workspace layout (floats):
//   deg_out : [0, N)
//   deg_in  : [N, 2N)
//   Tx_o    : [2N, 2N + 32N)
//   Tx_i    : [2N + 32N, 2N + 64N)
// total = 66*N floats = 13.2 MB
#define WS_DEG_OUT 0
#define WS_DEG_IN  (N_NODES)
#define WS_TXO     (2 * N_NODES)
#define WS_TXI     (2 * N_NODES + 32 * N_NODES)
#define WS_TOTAL_FLOATS (66 * N_NODES)

__global__ void zero_kernel(float4* __restrict__ p, int n4) {
    int i = blockIdx.x * blockDim.x + threadIdx.x;
    int stride = gridDim.x * blockDim.x;
    for (; i < n4; i += stride) p[i] = make_float4(0.f, 0.f, 0.f, 0.f);
}

__global__ void degree_kernel(const int* __restrict__ ei, const float* __restrict__ ew,
                              float* __restrict__ deg_out, float* __restrict__ deg_in) {
    int e = blockIdx.x * blockDim.x + threadIdx.x;
    if (e >= N_EDGES) return;
    int r = ei[e];
    int c = ei[N_EDGES + e];
    float w = ew[e];
    atomicAdd(&deg_out[r], w);
    atomicAdd(&deg_in[c], w);
}

__global__ void recip_kernel(float* __restrict__ deg, int n) {
    int i = blockIdx.x * blockDim.x + threadIdx.x;
    if (i >= n) return;
    float v = deg[i];
    deg[i] = (v != 0.f) ? (1.f / v) : 0.f;
}

// 8 threads per edge; each thread handles 4 channels (one float4).
__global__ void edge_kernel(const int* __restrict__ ei, const float* __restrict__ ew,
                            const float4* __restrict__ x4,
                            const float* __restrict__ rdeg_out,
                            const float* __restrict__ rdeg_in,
                            float* __restrict__ txo, float* __restrict__ txi) {
    int tid = blockIdx.x * blockDim.x + threadIdx.x;
    int e = tid >> 3;
    if (e >= N_EDGES) return;
    int q = tid & 7;
    int r = ei[e];
    int c = ei[N_EDGES + e];
    float w = ew[e];
    float co = w * rdeg_out[r];  // forward:  w / deg_out[row]
    float ci = w * rdeg_in[c];   // backward: w / deg_in[col]

    // forward dir: Tx_o[col] += co * x[row]
    float4 xr = x4[r * 8 + q];
    int bo = c * 32 + q * 4;
    atomicAdd(&txo[bo + 0], co * xr.x);
    atomicAdd(&txo[bo + 1], co * xr.y);
    atomicAdd(&txo[bo + 2], co * xr.z);
    atomicAdd(&txo[bo + 3], co * xr.w);

    // backward dir: Tx_i[row] += ci * x[col]
    float4 xc = x4[c * 8 + q];
    int bi = r * 32 + q * 4;
    atomicAdd(&txi[bi + 0], ci * xc.x);
    atomicAdd(&txi[bi + 1], ci * xc.y);
    atomicAdd(&txi[bi + 2], ci * xc.z);
    atomicAdd(&txi[bi + 3], ci * xc.w);
}

// Fused dense epilogue: for each node,
//   a_z = [x|Txo|Txi] @ Wz_eff + bz ; a_h likewise
//   Z = sigmoid(a_z); Ht = tanh(a_h); H = (1-Z)*Ht; out = relu(H) @ Wlin + blin
// Block = 256 threads = 4 nodes x 64 output channels (one wave per node).
// Weight slab layout k = slab*32 + c:
//   slab 0 (identity term, rows 0..31 of W[0,0]+W[1,0])
//   slab 1 (Tx_o term,   rows 0..31 of W[0,1])
//   slab 2 (Tx_i term,   rows 0..31 of W[1,1])
// W flat index for [d][k][c][o] (shape 2,2,96,64): ((d*2+k)*96+c)*64+o
__global__ __launch_bounds__(256) void dense_kernel(
    const float* __restrict__ x,
    const float* __restrict__ txo, const float* __restrict__ txi,
    const float* __restrict__ Wz, const float* __restrict__ bz,
    const float* __restrict__ Wh, const float* __restrict__ bh,
    const float* __restrict__ Wlin, const float* __restrict__ blin,
    float* __restrict__ out) {
    __shared__ float2 s_w[96 * 64];  // (wz, wh) interleaved, 48 KB
    __shared__ float s_in[4 * 96];

    int tid = threadIdx.x;
    for (int idx = tid; idx < 96 * 64; idx += 256) {
        int k = idx >> 6, o = idx & 63;
        int slab = k >> 5, c = k & 31;
        float wz, wh;
        if (slab == 0) {
            wz = Wz[c * 64 + o] + Wz[(2 * 96 + c) * 64 + o];
            wh = Wh[c * 64 + o] + Wh[(2 * 96 + c) * 64 + o];
        } else if (slab == 1) {
            wz = Wz[(96 + c) * 64 + o];
            wh = Wh[(96 + c) * 64 + o];
        } else {
            wz = Wz[(3 * 96 + c) * 64 + o];
            wh = Wh[(3 * 96 + c) * 64 + o];
        }
        s_w[idx] = make_float2(wz, wh);
    }

    int node0 = blockIdx.x * 4;  // N = 50000 divides evenly by 4 * 12500
    for (int idx = tid; idx < 4 * 96; idx += 256) {
        int nl = idx / 96, ch = idx - nl * 96;
        int node = node0 + nl;
        float v;
        if (ch < 32) v = x[node * 32 + ch];
        else if (ch < 64) v = txo[node * 32 + (ch - 32)];
        else v = txi[node * 32 + (ch - 64)];
        s_in[idx] = v;
    }
    __syncthreads();

    int nl = tid >> 6, o = tid & 63;
    int node = node0 + nl;
    float accz = bz[o], acch = bh[o];
    const float* xin = &s_in[nl * 96];
#pragma unroll
    for (int k = 0; k < 96; k += 4) {
        float4 xk = *(const float4*)(xin + k);
        float2 w0 = s_w[(k + 0) * 64 + o];
        float2 w1 = s_w[(k + 1) * 64 + o];
        float2 w2 = s_w[(k + 2) * 64 + o];
        float2 w3 = s_w[(k + 3) * 64 + o];
        accz += xk.x * w0.x + xk.y * w1.x + xk.z * w2.x + xk.w * w3.x;
        acch += xk.x * w0.y + xk.y * w1.y + xk.z * w2.y + xk.w * w3.y;
    }
    float z = 1.f / (1.f + __expf(-accz));
    float ht = tanhf(acch);
    float Hv = (1.f - z) * ht;
    float rr = fmaxf(Hv, 0.f) * Wlin[o];
#pragma unroll
    for (int off = 32; off > 0; off >>= 1)
        rr += __shfl_down(rr, off, 64);
    if (o == 0) out[node] = rr + blin[0];
}

extern "C" void kernel_launch(void* const* d_in, const int* in_sizes, int n_in,
                              void* d_out, int out_size, void* d_ws, size_t ws_size,
                              hipStream_t stream) {
    const float* x = (const float*)d_in[0];
    const int* ei = (const int*)d_in[1];
    const float* ew = (const float*)d_in[2];
    const float* Wz = (const float*)d_in[3];
    const float* bz = (const float*)d_in[4];
    // d_in[5] = Wr, d_in[6] = br : dead (H0 == 0 makes R unused)
    const float* Wh = (const float*)d_in[7];
    const float* bh = (const float*)d_in[8];
    const float* Wlin = (const float*)d_in[9];
    const float* blin = (const float*)d_in[10];
    float* out = (float*)d_out;
    float* ws = (float*)d_ws;

    float* deg_out = ws + WS_DEG_OUT;
    float* deg_in = ws + WS_DEG_IN;
    float* txo = ws + WS_TXO;
    float* txi = ws + WS_TXI;

    // 1. zero degrees + Tx buffers (ws is poisoned with 0xAA before every call)
    {
        int n4 = WS_TOTAL_FLOATS / 4;
        int blocks = (n4 + 255) / 256;
        if (blocks > 4096) blocks = 4096;
        zero_kernel<<<blocks, 256, 0, stream>>>((float4*)ws, n4);
    }
    // 2. degrees
    degree_kernel<<<(N_EDGES + 255) / 256, 256, 0, stream>>>(ei, ew, deg_out, deg_in);
    // 3. reciprocal degrees (in place)
    recip_kernel<<<(2 * N_NODES + 255) / 256, 256, 0, stream>>>(ws + WS_DEG_OUT, 2 * N_NODES);
    // 4. edge scatter (8 threads / edge)
    edge_kernel<<<(N_EDGES * 8) / 256, 256, 0, stream>>>(ei, ew, (const float4*)x,
                                                         deg_out, deg_in, txo, txi);
    // 5. fused dense epilogue
    dense_kernel<<<N_NODES / 4, 256, 0, stream>>>(x, txo, txi, Wz, bz, Wh, bh, Wlin, blin, out);
}

// Round 2
// 1117.657 us; speedup vs baseline: 1.6770x; 1.6770x over previous
//
#include <hip/hip_runtime.h>
#include <math.h>

#define N_NODES 50000
#define N_EDGES 1600000
#define IN_CH 32
#define HID 64

// ---------------- workspace layout (all element offsets multiples of 4 => 16B aligned)
// floats unless noted (int arrays alias the same buffer)
#define WS_DEG_OUT   0          // 50000 f   (becomes reciprocal after recip_kernel)
#define WS_DEG_IN    50000      // 50000 f
#define WS_CNT_COL   100000     // 50000 i
#define WS_CNT_ROW   150000     // 50000 i
#define WS_OFFS_COL  200000     // 50001 i (padded to 50004)
#define WS_OFFS_ROW  250004     // 50001 i (padded)
#define WS_CUR_COL   300008     // 50000 i
#define WS_CUR_ROW   350008     // 50000 i
#define WS_SRC_COL   400008     // 1600000 i
#define WS_SRC_ROW   2000008    // 1600000 i
#define WS_COEF_COL  3600008    // 1600000 f
#define WS_COEF_ROW  5200008    // 1600000 f
#define WS_TXO       6800008    // 1600000 f (50000 x 32)
#define WS_TXI       8400008    // 1600000 f
#define WS_TOTAL     10000008   // 40.0 MB

__global__ void zero_kernel(float4* __restrict__ p, int n4) {
    int i = blockIdx.x * blockDim.x + threadIdx.x;
    int stride = gridDim.x * blockDim.x;
    for (; i < n4; i += stride) p[i] = make_float4(0.f, 0.f, 0.f, 0.f);
}

// degrees + bucket counts: 4 atomics / edge (6.4M total, vs 102.4M before)
__global__ void deg_cnt_kernel(const int* __restrict__ ei, const float* __restrict__ ew,
                               float* __restrict__ deg_out, float* __restrict__ deg_in,
                               int* __restrict__ cnt_col, int* __restrict__ cnt_row) {
    int e = blockIdx.x * blockDim.x + threadIdx.x;
    if (e >= N_EDGES) return;
    int r = ei[e];
    int c = ei[N_EDGES + e];
    float w = ew[e];
    atomicAdd(&deg_out[r], w);
    atomicAdd(&deg_in[c], w);
    atomicAdd(&cnt_col[c], 1);
    atomicAdd(&cnt_row[r], 1);
}

__global__ void recip_kernel(float* __restrict__ deg, int n) {
    int i = blockIdx.x * blockDim.x + threadIdx.x;
    if (i >= n) return;
    float v = deg[i];
    deg[i] = (v != 0.f) ? (1.f / v) : 0.f;
}

// Exclusive scan of 50000 counts -> offs (+ total at offs[n]) + copy to cur.
// One 1024-thread block per array; blockIdx.x selects {col,row}.
__global__ __launch_bounds__(1024) void scan_kernel(int* __restrict__ ws_i) {
    const int n = N_NODES;
    const int T = 1024, CH = (n + T - 1) / T;  // 49
    __shared__ int s[1024];
    const int* cnt = ws_i + (blockIdx.x == 0 ? WS_CNT_COL : WS_CNT_ROW);
    int* offs = ws_i + (blockIdx.x == 0 ? WS_OFFS_COL : WS_OFFS_ROW);
    int* cur = ws_i + (blockIdx.x == 0 ? WS_CUR_COL : WS_CUR_ROW);

    int t = threadIdx.x;
    int beg = t * CH, end = min(beg + CH, n);
    int part = 0;
    for (int i = beg; i < end; ++i) part += cnt[i];
    s[t] = part;
    __syncthreads();
    // Hillis-Steele inclusive scan
    for (int off = 1; off < T; off <<= 1) {
        int v = (t >= off) ? s[t - off] : 0;
        __syncthreads();
        s[t] += v;
        __syncthreads();
    }
    int prefix = s[t] - part;  // exclusive
    int run = prefix;
    for (int i = beg; i < end; ++i) {
        offs[i] = run;
        cur[i] = run;
        run += cnt[i];
    }
    if (t == T - 1) offs[n] = s[T - 1];
}

// place (src, coef) into the two bucket-sorted layouts; 2 atomics / edge
__global__ void scatter_kernel(const int* __restrict__ ei, const float* __restrict__ ew,
                               const float* __restrict__ rdeg_out, const float* __restrict__ rdeg_in,
                               int* __restrict__ cur_col, int* __restrict__ cur_row,
                               int* __restrict__ src_col, float* __restrict__ coef_col,
                               int* __restrict__ src_row, float* __restrict__ coef_row) {
    int e = blockIdx.x * blockDim.x + threadIdx.x;
    if (e >= N_EDGES) return;
    int r = ei[e];
    int c = ei[N_EDGES + e];
    float w = ew[e];
    float co = w * rdeg_out[r];  // forward:  w / deg_out[row], lands at node col
    float ci = w * rdeg_in[c];   // backward: w / deg_in[col],  lands at node row
    int p = atomicAdd(&cur_col[c], 1);
    src_col[p] = r;
    coef_col[p] = co;
    int q = atomicAdd(&cur_row[r], 1);
    src_row[q] = c;
    coef_row[q] = ci;
}

// register-accumulating gather: 8 lanes per node, one float4 of channels each.
// blocks [0,1563) -> dir 0 (Tx_o via col lists), [1563,3126) -> dir 1 (Tx_i via row lists)
#define GROUPS_PER_BLOCK 32
#define BLOCKS_PER_DIR ((N_NODES + GROUPS_PER_BLOCK - 1) / GROUPS_PER_BLOCK)  // 1563
__global__ __launch_bounds__(256) void gather_kernel(
    const float4* __restrict__ x4, const int* __restrict__ ws_i, float* __restrict__ ws_f) {
    int b = blockIdx.x;
    int dir = (b >= BLOCKS_PER_DIR) ? 1 : 0;
    int node = (b - dir * BLOCKS_PER_DIR) * GROUPS_PER_BLOCK + (threadIdx.x >> 3);
    if (node >= N_NODES) return;
    int lane = threadIdx.x & 7;

    const int* offs = ws_i + (dir == 0 ? WS_OFFS_COL : WS_OFFS_ROW);
    const int* src = ws_i + (dir == 0 ? WS_SRC_COL : WS_SRC_ROW);
    const float* coef = ws_f + (dir == 0 ? WS_COEF_COL : WS_COEF_ROW);
    float4* outp = (float4*)(ws_f + (dir == 0 ? WS_TXO : WS_TXI));

    int p = offs[node], end = offs[node + 1];
    float4 acc = make_float4(0.f, 0.f, 0.f, 0.f);
    // 2-way unrolled for load ILP
    for (; p + 1 < end; p += 2) {
        int s0 = src[p], s1 = src[p + 1];
        float c0 = coef[p], c1 = coef[p + 1];
        float4 a = x4[s0 * 8 + lane];
        float4 bb = x4[s1 * 8 + lane];
        acc.x += c0 * a.x + c1 * bb.x;
        acc.y += c0 * a.y + c1 * bb.y;
        acc.z += c0 * a.z + c1 * bb.z;
        acc.w += c0 * a.w + c1 * bb.w;
    }
    if (p < end) {
        int s0 = src[p];
        float c0 = coef[p];
        float4 a = x4[s0 * 8 + lane];
        acc.x += c0 * a.x;
        acc.y += c0 * a.y;
        acc.z += c0 * a.z;
        acc.w += c0 * a.w;
    }
    outp[node * 8 + lane] = acc;
}

// Fused dense epilogue (unchanged from round 1): per node
//   Z = sigmoid([x|Txo|Txi] @ Wz_eff + bz); Ht = tanh(... Wh ...);
//   H = (1-Z)*Ht; out = relu(H) @ Wlin + blin
__global__ __launch_bounds__(256) void dense_kernel(
    const float* __restrict__ x,
    const float* __restrict__ txo, const float* __restrict__ txi,
    const float* __restrict__ Wz, const float* __restrict__ bz,
    const float* __restrict__ Wh, const float* __restrict__ bh,
    const float* __restrict__ Wlin, const float* __restrict__ blin,
    float* __restrict__ out) {
    __shared__ float2 s_w[96 * 64];  // (wz, wh) interleaved, 48 KB
    __shared__ float s_in[4 * 96];

    int tid = threadIdx.x;
    for (int idx = tid; idx < 96 * 64; idx += 256) {
        int k = idx >> 6, o = idx & 63;
        int slab = k >> 5, c = k & 31;
        float wz, wh;
        if (slab == 0) {
            wz = Wz[c * 64 + o] + Wz[(2 * 96 + c) * 64 + o];
            wh = Wh[c * 64 + o] + Wh[(2 * 96 + c) * 64 + o];
        } else if (slab == 1) {
            wz = Wz[(96 + c) * 64 + o];
            wh = Wh[(96 + c) * 64 + o];
        } else {
            wz = Wz[(3 * 96 + c) * 64 + o];
            wh = Wh[(3 * 96 + c) * 64 + o];
        }
        s_w[idx] = make_float2(wz, wh);
    }

    int node0 = blockIdx.x * 4;
    for (int idx = tid; idx < 4 * 96; idx += 256) {
        int nl = idx / 96, ch = idx - nl * 96;
        int node = node0 + nl;
        float v;
        if (ch < 32) v = x[node * 32 + ch];
        else if (ch < 64) v = txo[node * 32 + (ch - 32)];
        else v = txi[node * 32 + (ch - 64)];
        s_in[idx] = v;
    }
    __syncthreads();

    int nl = tid >> 6, o = tid & 63;
    int node = node0 + nl;
    float accz = bz[o], acch = bh[o];
    const float* xin = &s_in[nl * 96];
#pragma unroll
    for (int k = 0; k < 96; k += 4) {
        float4 xk = *(const float4*)(xin + k);
        float2 w0 = s_w[(k + 0) * 64 + o];
        float2 w1 = s_w[(k + 1) * 64 + o];
        float2 w2 = s_w[(k + 2) * 64 + o];
        float2 w3 = s_w[(k + 3) * 64 + o];
        accz += xk.x * w0.x + xk.y * w1.x + xk.z * w2.x + xk.w * w3.x;
        acch += xk.x * w0.y + xk.y * w1.y + xk.z * w2.y + xk.w * w3.y;
    }
    float z = 1.f / (1.f + __expf(-accz));
    float ht = tanhf(acch);
    float Hv = (1.f - z) * ht;
    float rr = fmaxf(Hv, 0.f) * Wlin[o];
#pragma unroll
    for (int off = 32; off > 0; off >>= 1)
        rr += __shfl_down(rr, off, 64);
    if (o == 0) out[node] = rr + blin[0];
}

extern "C" void kernel_launch(void* const* d_in, const int* in_sizes, int n_in,
                              void* d_out, int out_size, void* d_ws, size_t ws_size,
                              hipStream_t stream) {
    const float* x = (const float*)d_in[0];
    const int* ei = (const int*)d_in[1];
    const float* ew = (const float*)d_in[2];
    const float* Wz = (const float*)d_in[3];
    const float* bz = (const float*)d_in[4];
    // d_in[5]=Wr, d_in[6]=br dead: H0==0 makes the reset gate a no-op
    const float* Wh = (const float*)d_in[7];
    const float* bh = (const float*)d_in[8];
    const float* Wlin = (const float*)d_in[9];
    const float* blin = (const float*)d_in[10];
    float* out = (float*)d_out;
    float* wf = (float*)d_ws;
    int* wi = (int*)d_ws;

    // 1. zero degrees + counts (200000 floats/ints); Tx needs no zeroing (gather writes fully)
    zero_kernel<<<196, 256, 0, stream>>>((float4*)wf, 200000 / 4);
    // 2. degrees + bucket counts
    deg_cnt_kernel<<<(N_EDGES + 255) / 256, 256, 0, stream>>>(
        ei, ew, wf + WS_DEG_OUT, wf + WS_DEG_IN, wi + WS_CNT_COL, wi + WS_CNT_ROW);
    // 3. reciprocal degrees in place
    recip_kernel<<<(2 * N_NODES + 255) / 256, 256, 0, stream>>>(wf + WS_DEG_OUT, 2 * N_NODES);
    // 4. counts -> offsets (+cur) for both orderings
    scan_kernel<<<2, 1024, 0, stream>>>(wi);
    // 5. bucket-sort edges (src, coef) by destination node, per direction
    scatter_kernel<<<(N_EDGES + 255) / 256, 256, 0, stream>>>(
        ei, ew, wf + WS_DEG_OUT, wf + WS_DEG_IN, wi + WS_CUR_COL, wi + WS_CUR_ROW,
        wi + WS_SRC_COL, wf + WS_COEF_COL, wi + WS_SRC_ROW, wf + WS_COEF_ROW);
    // 6. atomic-free register-accumulating gather -> Tx_o, Tx_i
    gather_kernel<<<2 * BLOCKS_PER_DIR, 256, 0, stream>>>((const float4*)x, wi, wf);
    // 7. fused dense epilogue
    dense_kernel<<<N_NODES / 4, 256, 0, stream>>>(
        x, wf + WS_TXO, wf + WS_TXI, Wz, bz, Wh, bh, Wlin, blin, out);
}